// Round 3
// baseline (553.328 us; speedup 1.0000x reference)
//
#include <hip/hip_runtime.h>

typedef __bf16 bf16;
typedef bf16 bf16x8 __attribute__((ext_vector_type(8)));
typedef bf16 bf16x4 __attribute__((ext_vector_type(4)));
typedef float f32x4 __attribute__((ext_vector_type(4)));

#define C_DIM 1024
#define T_DIM 2048
#define B_DIM 4
#define H_DIM 4096

// ---------------------------------------------------------------------------
// async global -> LDS, 16B per lane. LDS dest is wave-uniform base + lane*16.
// ---------------------------------------------------------------------------
__device__ inline void gld_lds16(const bf16* g, bf16* l) {
    __builtin_amdgcn_global_load_lds(
        (const __attribute__((address_space(1))) unsigned int*)g,
        (__attribute__((address_space(3))) unsigned int*)l,
        16, 0, 0);
}

// fast tanh-gelu: u * sigmoid(1.5957692*u + 0.07135481*u^3)
__device__ inline float fast_gelu(float u) {
    float k2 = 1.5957691216057308f * u + 0.07135480895843475f * u * u * u;
    float t = __expf(-k2);
    return u * __builtin_amdgcn_rcpf(1.0f + t);
}

// ---------------------------------------------------------------------------
// 8/4-phase 256-row-tile GEMM:  C = alpha * A[M,K] @ Bt[N,K]^T (+bias)(+gelu|+resid)
//
// BM=256, BN in {256,128}, BK=64, 8 waves, 512 threads, MFMA 16x16x32 bf16.
//   BN=256: waves 2x4 (wave tile 128x64), 4 phases/K-tile, 16 MFMA/phase
//   BN=128: waves 4x2 (wave tile  64x64), 2 phases/K-tile, 16 MFMA/phase
//
// LDS: A [2 buf][2 ks][256 rows][32 k] bf16 (64KB); B [2][2][BN][32].
// XOR swizzle (verified R2: SQ_LDS_BANK_CONFLICT = 0): 16B chunk c of row r
// stored at slot c ^ ((r>>1)&3); read chunk = lc ^ ((lr>>1)&3) (free, folds
// into base); gld_lds dest stays LINEAR, global SOURCE chunk pre-swizzled.
//
// Pipeline (R3 rework): every LDS slot is staged exactly 6 phases before its
// first read. Waits are uniform+minimal so the wait never gates on a load
// issued fewer than 6 phases ago:
//   BN=256 (2 gld/phase): VMC(10) at p1,p3,p5,p7 tops; tail ladder 10/8/4/0.
//   BN=128 (3 gld/phase): VMC(6) at every phase top;   tail ladder 6/6/3/0.
// Restage of each slot happens in the phase right after its last read
// (write-after-read separated by >=1 s_barrier). No sched_barrier: ds_reads
// are compiler IR, fine-grained lgkmcnt insertion is handled by the backend.
// ---------------------------------------------------------------------------
template <int EPI, typename OutT, int BN>
__launch_bounds__(512, 2)
__global__ void gemm8p(const bf16* __restrict__ A, int lda, long long sA,
                       const bf16* __restrict__ Bt, int ldb, long long sB,
                       OutT* __restrict__ Cout, int ldc, long long sC,
                       const float* __restrict__ bias,
                       const float* __restrict__ resid, long long sR,
                       float alpha, int K) {
    constexpr int BQ = BN / 128;            // gld_lds issues per B half-slab
    constexpr int FM = (BN == 256) ? 8 : 4; // row fragments per wave
    constexpr int AW = (BN == 256) ? 128 : 64;  // rows per wave strip

    const int z = blockIdx.z;
    A += (long long)z * sA;
    Bt += (long long)z * sB;
    Cout += (long long)z * sC;
    if (resid) resid += (long long)z * sR;

    // bijective XCD swizzle (all our xy-grids are multiples of 8)
    const int gx = gridDim.x;
    const int nwg = gx * gridDim.y;
    int bid = blockIdx.y * gx + blockIdx.x;
    bid = (bid & 7) * (nwg >> 3) + (bid >> 3);
    const int rowBase = (bid % gx) * 256;
    const int colBase = (bid / gx) * BN;

    __shared__ __align__(16) bf16 As[2 * 2 * 256 * 32];
    __shared__ __align__(16) bf16 Bs[2 * 2 * BN * 32];

    const int tid = threadIdx.x;
    const int w = tid >> 6;
    const int lane = tid & 63;
    const int wm = (BN == 256) ? (w >> 2) : (w >> 1);
    const int wn = (BN == 256) ? (w & 3) : (w & 1);
    const int lr = lane & 15, lc = lane >> 4;

    // staging: lane covers (row = tid>>2, swizzled 16B chunk) of a 128-row slab
    const int gchunk = (tid & 3) ^ ((tid >> 3) & 3);
    const bf16* Ag = A + (size_t)(rowBase + (tid >> 2)) * lda + gchunk * 8;
    const bf16* Bg = Bt + (size_t)(colBase + (tid >> 2)) * ldb + gchunk * 8;
    const size_t ldaL = (size_t)lda, ldbL = (size_t)ldb;
    bf16* AsW = As + w * 512;   // wave slice inside each staged 8KB half-slab
    bf16* BsW = Bs + w * 512;

    // fragment read bases (element offsets); read chunk XOR folds into base
    const int rchunk = lc ^ ((lr >> 1) & 3);
    const int aBase = wm * (AW * 32) + lr * 32 + rchunk * 8;
    const int bBase = wn * 2048 + lr * 32 + rchunk * 8;

#define STAGE_A(buf, ks, tau) do {                                         \
        const bf16* _g = Ag + (size_t)(tau) * 64 + (ks) * 32;              \
        bf16* _l = AsW + ((buf) * 2 + (ks)) * 8192;                        \
        gld_lds16(_g, _l);                                                 \
        gld_lds16(_g + 128 * ldaL, _l + 4096);                             \
    } while (0)

#define STAGE_B(buf, ks, tau) do {                                         \
        const bf16* _g = Bg + (size_t)(tau) * 64 + (ks) * 32;              \
        bf16* _l = BsW + ((buf) * 2 + (ks)) * (BN * 32);                   \
        gld_lds16(_g, _l);                                                 \
        if constexpr (BQ == 2) gld_lds16(_g + 128 * ldbL, _l + 4096);      \
    } while (0)

#define LOAD_A(buf, ks, rh) do {                                           \
        _Pragma("unroll")                                                  \
        for (int i = 0; i < 4; i++)                                        \
            af[i] = *(const bf16x8*)(As + aBase + ((buf) * 2 + (ks)) * 8192 \
                                     + (rh) * 2048 + i * 512);             \
    } while (0)

#define LOAD_B(dst, buf, ks) do {                                          \
        _Pragma("unroll")                                                  \
        for (int j = 0; j < 4; j++)                                        \
            dst[j] = *(const bf16x8*)(Bs + bBase + ((buf) * 2 + (ks)) * (BN * 32) \
                                      + j * 512);                          \
    } while (0)

#define MMA(rh, bfr) do {                                                  \
        __builtin_amdgcn_s_setprio(1);                                     \
        _Pragma("unroll")                                                  \
        for (int i = 0; i < 4; i++)                                        \
            _Pragma("unroll")                                              \
            for (int j = 0; j < 4; j++)                                    \
                acc[(rh) * 4 + i][j] = __builtin_amdgcn_mfma_f32_16x16x32_bf16( \
                    af[i], bfr[j], acc[(rh) * 4 + i][j], 0, 0, 0);         \
        __builtin_amdgcn_s_setprio(0);                                     \
    } while (0)

#define BAR() __builtin_amdgcn_s_barrier()
#define VMC(n) asm volatile("s_waitcnt vmcnt(" #n ")" ::: "memory")

    f32x4 acc[FM][4] = {};
    bf16x8 af[4], b0[4], b1[4];

    const int NT = K >> 6;  // K in {1024,2048,4096} -> NT even, >= 16

    if constexpr (BN == 256) {
        // ---- prologue: tile0 fully, tile1 B-k0/A-k0/B-k1 (A11 at p1) ----
        STAGE_B(0, 0, 0);
        STAGE_A(0, 0, 0);
        STAGE_B(0, 1, 0);
        STAGE_A(0, 1, 0);
        STAGE_B(1, 0, 1);
        STAGE_A(1, 0, 1);
        STAGE_B(1, 1, 1);
        BAR();

        for (int t = 0; t < NT - 2; t += 2) {
            // p1
            VMC(10);
            LOAD_A(0, 0, 0); LOAD_B(b0, 0, 0);
            STAGE_A(1, 1, t + 1);
            BAR(); MMA(0, b0); BAR();
            // p2
            LOAD_A(0, 0, 1);
            STAGE_B(0, 0, t + 2);
            BAR(); MMA(1, b0); BAR();
            // p3
            VMC(10);
            LOAD_A(0, 1, 0); LOAD_B(b1, 0, 1);
            STAGE_A(0, 0, t + 2);
            BAR(); MMA(0, b1); BAR();
            // p4
            LOAD_A(0, 1, 1);
            STAGE_B(0, 1, t + 2);
            BAR(); MMA(1, b1); BAR();
            // p5
            VMC(10);
            LOAD_A(1, 0, 0); LOAD_B(b0, 1, 0);
            STAGE_A(0, 1, t + 2);
            BAR(); MMA(0, b0); BAR();
            // p6
            LOAD_A(1, 0, 1);
            STAGE_B(1, 0, t + 3);
            BAR(); MMA(1, b0); BAR();
            // p7
            VMC(10);
            LOAD_A(1, 1, 0); LOAD_B(b1, 1, 1);
            STAGE_A(1, 0, t + 3);
            BAR(); MMA(0, b1); BAR();
            // p8
            LOAD_A(1, 1, 1);
            STAGE_B(1, 1, t + 3);
            BAR(); MMA(1, b1); BAR();
        }
        // ---- tail: tiles NT-2 (buf0), NT-1 (buf1); wait ladder 10/8/4/0 ----
        {
            const int t = NT - 2;
            VMC(10);
            LOAD_A(0, 0, 0); LOAD_B(b0, 0, 0);
            STAGE_A(1, 1, t + 1);
            BAR(); MMA(0, b0); BAR();
            LOAD_A(0, 0, 1);
            BAR(); MMA(1, b0); BAR();
            VMC(8);
            LOAD_A(0, 1, 0); LOAD_B(b1, 0, 1);
            BAR(); MMA(0, b1); BAR();
            LOAD_A(0, 1, 1);
            BAR(); MMA(1, b1); BAR();
            VMC(4);
            LOAD_A(1, 0, 0); LOAD_B(b0, 1, 0);
            BAR(); MMA(0, b0); BAR();
            LOAD_A(1, 0, 1);
            BAR(); MMA(1, b0); BAR();
            VMC(0);
            LOAD_A(1, 1, 0); LOAD_B(b1, 1, 1);
            BAR(); MMA(0, b1); BAR();
            LOAD_A(1, 1, 1);
            MMA(1, b1);
        }
    } else {
        // ---- BN=128: 2 phases per K-tile, 16 MFMA each, 3 gld/phase ----
        STAGE_A(0, 0, 0);
        STAGE_B(0, 0, 0);
        STAGE_A(0, 1, 0);
        STAGE_B(0, 1, 0);
        STAGE_A(1, 0, 1);
        STAGE_B(1, 0, 1);
        BAR();

        for (int t = 0; t < NT - 2; t += 2) {
            // p1: tile t, ks0
            VMC(6);
            LOAD_A(0, 0, 0); LOAD_B(b0, 0, 0);
            STAGE_A(1, 1, t + 1); STAGE_B(1, 1, t + 1);
            BAR(); MMA(0, b0); BAR();
            // p2: tile t, ks1
            VMC(6);
            LOAD_A(0, 1, 0); LOAD_B(b1, 0, 1);
            STAGE_A(0, 0, t + 2); STAGE_B(0, 0, t + 2);
            BAR(); MMA(0, b1); BAR();
            // p3: tile t+1, ks0
            VMC(6);
            LOAD_A(1, 0, 0); LOAD_B(b0, 1, 0);
            STAGE_A(0, 1, t + 2); STAGE_B(0, 1, t + 2);
            BAR(); MMA(0, b0); BAR();
            // p4: tile t+1, ks1
            VMC(6);
            LOAD_A(1, 1, 0); LOAD_B(b1, 1, 1);
            STAGE_A(1, 0, t + 3); STAGE_B(1, 0, t + 3);
            BAR(); MMA(0, b1); BAR();
        }
        // ---- tail: wait ladder 6/6/3/0 ----
        {
            const int t = NT - 2;
            VMC(6);
            LOAD_A(0, 0, 0); LOAD_B(b0, 0, 0);
            STAGE_A(1, 1, t + 1); STAGE_B(1, 1, t + 1);
            BAR(); MMA(0, b0); BAR();
            VMC(6);
            LOAD_A(0, 1, 0); LOAD_B(b1, 0, 1);
            BAR(); MMA(0, b1); BAR();
            VMC(3);
            LOAD_A(1, 0, 0); LOAD_B(b0, 1, 0);
            BAR(); MMA(0, b0); BAR();
            VMC(0);
            LOAD_A(1, 1, 0); LOAD_B(b1, 1, 1);
            MMA(0, b1);
        }
    }

#undef STAGE_A
#undef STAGE_B
#undef LOAD_A
#undef LOAD_B
#undef MMA
#undef BAR
#undef VMC

    // ---- epilogue. C/D layout (16x16x32): col = lane&15, row = (lane>>4)*4 + reg ----
    float bval[4];
#pragma unroll
    for (int j = 0; j < 4; j++)
        bval[j] = bias ? bias[colBase + wn * 64 + j * 16 + lr] : 0.0f;

#pragma unroll
    for (int fi = 0; fi < FM; fi++) {
        const int row = rowBase + wm * AW + fi * 16 + lc * 4;
#pragma unroll
        for (int fj = 0; fj < 4; fj++) {
            const int col = colBase + wn * 64 + fj * 16 + lr;
#pragma unroll
            for (int r = 0; r < 4; r++) {
                float v = acc[fi][fj][r] * alpha + bval[fj];
                if constexpr (EPI == 1) v = fast_gelu(v);
                if constexpr (EPI == 2) v += resid[(size_t)(row + r) * ldc + col];
                Cout[(size_t)(row + r) * ldc + col] = (OutT)v;
            }
        }
    }
}

// ---------------------------------------------------------------------------
// LayerNorm over last dim (C=1024), fp32 in -> bf16 out. One block per row.
// ---------------------------------------------------------------------------
__launch_bounds__(256)
__global__ void ln_kernel(const float* __restrict__ x, const float* __restrict__ g,
                          const float* __restrict__ b, bf16* __restrict__ out) {
    __shared__ float red[4];
    const int row = blockIdx.x;
    const int tid = threadIdx.x;
    const float4* xr = (const float4*)(x + (size_t)row * C_DIM);
    float4 v = xr[tid];
    float s = v.x + v.y + v.z + v.w;
#pragma unroll
    for (int m = 32; m; m >>= 1) s += __shfl_xor(s, m, 64);
    if ((tid & 63) == 0) red[tid >> 6] = s;
    __syncthreads();
    const float mu = (red[0] + red[1] + red[2] + red[3]) * (1.0f / C_DIM);
    const float dx = v.x - mu, dy = v.y - mu, dz = v.z - mu, dw = v.w - mu;
    float q = dx * dx + dy * dy + dz * dz + dw * dw;
#pragma unroll
    for (int m = 32; m; m >>= 1) q += __shfl_xor(q, m, 64);
    __syncthreads();
    if ((tid & 63) == 0) red[tid >> 6] = q;
    __syncthreads();
    const float var = (red[0] + red[1] + red[2] + red[3]) * (1.0f / C_DIM);
    const float rs = rsqrtf(var + 1e-5f);
    const float4 gg = ((const float4*)g)[tid];
    const float4 bb = ((const float4*)b)[tid];
    bf16x4 o;
    o[0] = (bf16)(dx * rs * gg.x + bb.x);
    o[1] = (bf16)(dy * rs * gg.y + bb.y);
    o[2] = (bf16)(dz * rs * gg.z + bb.z);
    o[3] = (bf16)(dw * rs * gg.w + bb.w);
    ((bf16x4*)(out + (size_t)row * C_DIM))[tid] = o;
}

// ---------------------------------------------------------------------------
// Row softmax: S row (T=2048 bf16) -> P row (bf16). One block per row.
// ---------------------------------------------------------------------------
__launch_bounds__(256)
__global__ void softmax_kernel(const bf16* __restrict__ S, bf16* __restrict__ P) {
    __shared__ float red[4];
    const size_t base = (size_t)blockIdx.x * T_DIM;
    const int tid = threadIdx.x;
    bf16x8 sv = ((const bf16x8*)(S + base))[tid];
    float e[8];
#pragma unroll
    for (int i = 0; i < 8; i++) e[i] = (float)sv[i];
    float mx = e[0];
#pragma unroll
    for (int i = 1; i < 8; i++) mx = fmaxf(mx, e[i]);
#pragma unroll
    for (int m = 32; m; m >>= 1) mx = fmaxf(mx, __shfl_xor(mx, m, 64));
    if ((tid & 63) == 0) red[tid >> 6] = mx;
    __syncthreads();
    mx = fmaxf(fmaxf(red[0], red[1]), fmaxf(red[2], red[3]));
    float s = 0.0f;
#pragma unroll
    for (int i = 0; i < 8; i++) {
        e[i] = __expf(e[i] - mx);
        s += e[i];
    }
#pragma unroll
    for (int m = 32; m; m >>= 1) s += __shfl_xor(s, m, 64);
    __syncthreads();
    if ((tid & 63) == 0) red[tid >> 6] = s;
    __syncthreads();
    const float inv = 1.0f / (red[0] + red[1] + red[2] + red[3]);
    bf16x8 p;
#pragma unroll
    for (int i = 0; i < 8; i++) p[i] = (bf16)(e[i] * inv);
    ((bf16x8*)(P + base))[tid] = p;
}

// ---------------------------------------------------------------------------
// Merged transpose+convert for all 4 weight matrices (fp32 [R,Cc] -> bf16 [Cc,R]).
// ---------------------------------------------------------------------------
__global__ void transpose_f2b_all(const float* __restrict__ s0, bf16* __restrict__ d0,
                                  const float* __restrict__ s1, bf16* __restrict__ d1,
                                  const float* __restrict__ s2, bf16* __restrict__ d2,
                                  const float* __restrict__ s3, bf16* __restrict__ d3) {
    __shared__ float tile[32][33];
    int id = blockIdx.x;
    const float* src;
    bf16* dst;
    int R, Cc, local;
    if (id < 3072)       { src = s0; dst = d0; R = 1024; Cc = 3072; local = id; }
    else if (id < 4096)  { src = s1; dst = d1; R = 1024; Cc = 1024; local = id - 3072; }
    else if (id < 8192)  { src = s2; dst = d2; R = 1024; Cc = 4096; local = id - 4096; }
    else                 { src = s3; dst = d3; R = 4096; Cc = 1024; local = id - 8192; }
    const int tilesX = Cc >> 5;
    const int bx = (local % tilesX) * 32;
    const int by = (local / tilesX) * 32;
    const int tx = threadIdx.x, ty = threadIdx.y;
    for (int i = ty; i < 32; i += 8)
        tile[i][tx] = src[(size_t)(by + i) * Cc + bx + tx];
    __syncthreads();
    for (int i = ty; i < 32; i += 8)
        dst[(size_t)(bx + i) * R + by + tx] = (bf16)tile[tx][i];
}

// Transpose bf16 [R, Cc] (ld=ldsrc) -> bf16 [Cc, R] (ld=R), batched via z.
__global__ void transpose_b2b(const bf16* __restrict__ src, int ldsrc, long long sstride,
                              bf16* __restrict__ dst, long long dstride, int R) {
    __shared__ bf16 tile[32][33];
    src += (long long)blockIdx.z * sstride;
    dst += (long long)blockIdx.z * dstride;
    const int bx = blockIdx.x * 32;
    const int by = blockIdx.y * 32;
    const int tx = threadIdx.x, ty = threadIdx.y;
    for (int i = ty; i < 32; i += 8)
        tile[i][tx] = src[(size_t)(by + i) * ldsrc + bx + tx];
    __syncthreads();
    for (int i = ty; i < 32; i += 8)
        dst[(size_t)(bx + i) * R + by + tx] = tile[tx][i];
}

// ---------------------------------------------------------------------------
extern "C" void kernel_launch(void* const* d_in, const int* in_sizes, int n_in,
                              void* d_out, int out_size, void* d_ws, size_t ws_size,
                              hipStream_t stream) {
    const float* x      = (const float*)d_in[0];
    const float* ln1_g  = (const float*)d_in[1];
    const float* ln1_b  = (const float*)d_in[2];
    const float* w_attn = (const float*)d_in[3];
    const float* b_attn = (const float*)d_in[4];
    const float* w_proj = (const float*)d_in[5];
    const float* b_proj = (const float*)d_in[6];
    const float* ln2_g  = (const float*)d_in[7];
    const float* ln2_b  = (const float*)d_in[8];
    const float* w_fc   = (const float*)d_in[9];
    const float* b_fc   = (const float*)d_in[10];
    const float* w_mlp  = (const float*)d_in[11];
    const float* b_mlp  = (const float*)d_in[12];
    float* out = (float*)d_out;

    const int M = B_DIM * T_DIM;  // 8192

    char* base = (char*)d_ws;
    size_t off = 0;
    auto alloc = [&](size_t bytes) -> char* {
        char* p = base + off;
        off += (bytes + 255) & ~(size_t)255;
        return p;
    };
    bf16* wT_attn = (bf16*)alloc((size_t)3072 * 1024 * 2);
    bf16* wT_proj = (bf16*)alloc((size_t)1024 * 1024 * 2);
    bf16* wT_fc   = (bf16*)alloc((size_t)4096 * 1024 * 2);
    bf16* wT_mlp  = (bf16*)alloc((size_t)1024 * 4096 * 2);
    bf16* h       = (bf16*)alloc((size_t)M * 1024 * 2);        // h1, reused as h2
    bf16* qkv     = (bf16*)alloc((size_t)M * 3072 * 2);
    bf16* vT      = (bf16*)alloc((size_t)B_DIM * 1024 * 2048 * 2);
    bf16* S       = (bf16*)alloc((size_t)B_DIM * 2048 * 2048 * 2);
    bf16* P       = (bf16*)alloc((size_t)B_DIM * 2048 * 2048 * 2);
    bf16* y       = (bf16*)alloc((size_t)M * 1024 * 2);
    float* x2     = (float*)alloc((size_t)M * 1024 * 4);
    bf16* act     = (bf16*)S;  // alias: S+P dead after PV; 67MB needed, S+P = 67MB

    const dim3 tb(32, 8);

    // weight transpose+convert, all 4 in one launch
    transpose_f2b_all<<<12288, tb, 0, stream>>>(w_attn, wT_attn, w_proj, wT_proj,
                                                w_fc, wT_fc, w_mlp, wT_mlp);

    // h = LN1(x)
    ln_kernel<<<M, 256, 0, stream>>>(x, ln1_g, ln1_b, h);

    // qkv = h @ w_attn + b_attn   [8192, 3072]
    gemm8p<0, bf16, 128><<<dim3(32, 24, 1), 512, 0, stream>>>(
        h, 1024, 0, wT_attn, 1024, 0, qkv, 3072, 0, b_attn, nullptr, 0, 1.0f, 1024);

    // vT[b] = v[b]^T   (v = qkv cols [2C,3C))
    transpose_b2b<<<dim3(1024 / 32, 2048 / 32, B_DIM), tb, 0, stream>>>(
        qkv + 2 * C_DIM, 3072, (long long)T_DIM * 3072, vT, (long long)C_DIM * T_DIM, T_DIM);

    // S[b] = q[b] @ k[b]^T * (1/32)   [2048, 2048] bf16
    gemm8p<0, bf16, 256><<<dim3(8, 8, B_DIM), 512, 0, stream>>>(
        qkv, 3072, (long long)T_DIM * 3072,
        qkv + C_DIM, 3072, (long long)T_DIM * 3072,
        S, 2048, (long long)T_DIM * T_DIM, nullptr, nullptr, 0, 0.03125f, 1024);

    // P = softmax(S) rows
    softmax_kernel<<<B_DIM * T_DIM, 256, 0, stream>>>(S, P);

    // y[b] = P[b] @ v[b]   [2048, 1024] bf16
    gemm8p<0, bf16, 128><<<dim3(8, 8, B_DIM), 512, 0, stream>>>(
        P, 2048, (long long)T_DIM * T_DIM,
        vT, 2048, (long long)C_DIM * T_DIM,
        y, 1024, (long long)T_DIM * C_DIM, nullptr, nullptr, 0, 1.0f, 2048);

    // x2 = y @ w_proj + b_proj + x   [8192, 1024] fp32
    gemm8p<2, float, 128><<<dim3(32, 8, 1), 512, 0, stream>>>(
        y, 1024, 0, wT_proj, 1024, 0, x2, 1024, 0, b_proj, x, 0, 1.0f, 1024);

    // h2 = LN2(x2)  (reuse h buffer)
    ln_kernel<<<M, 256, 0, stream>>>(x2, ln2_g, ln2_b, h);

    // act = gelu(h2 @ w_fc + b_fc)   [8192, 4096] bf16
    gemm8p<1, bf16, 256><<<dim3(32, 16, 1), 512, 0, stream>>>(
        h, 1024, 0, wT_fc, 1024, 0, act, 4096, 0, b_fc, nullptr, 0, 1.0f, 1024);

    // out = act @ w_mlp_proj + b_mlp_proj + x2   [8192, 1024] fp32
    gemm8p<2, float, 128><<<dim3(32, 8, 1), 512, 0, stream>>>(
        act, 4096, 0, wT_mlp, 4096, 0, out, 1024, 0, b_mlp, x2, 0, 1.0f, 4096);
}

// Round 4
// 518.960 us; speedup vs baseline: 1.0662x; 1.0662x over previous
//
#include <hip/hip_runtime.h>

typedef __bf16 bf16;
typedef bf16 bf16x8 __attribute__((ext_vector_type(8)));
typedef bf16 bf16x4 __attribute__((ext_vector_type(4)));
typedef float f32x4 __attribute__((ext_vector_type(4)));

#define C_DIM 1024
#define T_DIM 2048
#define B_DIM 4
#define H_DIM 4096

// ---------------------------------------------------------------------------
// async global -> LDS, 16B per lane. LDS dest is wave-uniform base + lane*16.
// ---------------------------------------------------------------------------
__device__ inline void gld_lds16(const bf16* g, bf16* l) {
    __builtin_amdgcn_global_load_lds(
        (const __attribute__((address_space(1))) unsigned int*)g,
        (__attribute__((address_space(3))) unsigned int*)l,
        16, 0, 0);
}

// fast tanh-gelu: u * sigmoid(1.5957692*u + 0.07135481*u^3)
__device__ inline float fast_gelu(float u) {
    float k2 = 1.5957691216057308f * u + 0.07135480895843475f * u * u * u;
    float t = __expf(-k2);
    return u * __builtin_amdgcn_rcpf(1.0f + t);
}

// ---------------------------------------------------------------------------
// 2-phase-per-K-tile 256-row GEMM: C = alpha*A[M,K]@Bt[N,K]^T (+bias)(+gelu|+resid)
//
// BM=256, BN in {256,128}, BK=64, 8 waves, 512 threads, MFMA 16x16x32 bf16.
//   BN=256: waves 2x4, wave tile 128x64, 32 MFMA/phase
//   BN=128: waves 4x2, wave tile  64x64, 16 MFMA/phase
// Phase = { VMC | ds_read A-strip + B-slot | stage one {A,B} slot | BAR |
//           setprio(1) MFMA setprio(0) | BAR }.
//
// LDS: A [2 buf][2 ks][256 rows][32 k] bf16 (64KB); B [2][2][BN][32].
// XOR swizzle (verified R2: SQ_LDS_BANK_CONFLICT = 0): 16B chunk c of row r
// stored at slot c ^ ((r>>1)&3); read chunk = lc ^ ((lr>>1)&3) (free, folds
// into base); gld_lds dest stays LINEAR, global SOURCE chunk pre-swizzled.
//
// Pipeline: slot (buf,ks) of tile t is staged 3 phases before its read and
// restaged one phase after its read (>=2 barriers separate write-after-read):
//   phase (t,0): read slot(buf,0);  stage slot(buf^1,1) for tile t+1
//   phase (t,1): read slot(buf,1);  stage slot(buf,0)   for tile t+2
// Steady-state waits (gld per phase g = 4 for BN=256, 3 for BN=128):
//   VMC(2g) at each phase top  -> loads from 3 phases ago have landed.
//   Tail ladder: 2g / 2g / g / 0.
// NO XCD swizzle: R3 measured it 3.6x-ing FETCH (each XCD streamed all of A
// through its private L2); natural round-robin already row-partitions A.
// ---------------------------------------------------------------------------
template <int EPI, typename OutT, int BN>
__launch_bounds__(512, 2)
__global__ void gemm8p(const bf16* __restrict__ A, int lda, long long sA,
                       const bf16* __restrict__ Bt, int ldb, long long sB,
                       OutT* __restrict__ Cout, int ldc, long long sC,
                       const float* __restrict__ bias,
                       const float* __restrict__ resid, long long sR,
                       float alpha, int K) {
    constexpr int BQ = BN / 128;            // gld_lds issues per B slot
    constexpr int FM = (BN == 256) ? 8 : 4; // row fragments per wave
    constexpr int AW = (BN == 256) ? 128 : 64;  // rows per wave strip

    const int z = blockIdx.z;
    A += (long long)z * sA;
    Bt += (long long)z * sB;
    Cout += (long long)z * sC;
    if (resid) resid += (long long)z * sR;

    const int rowBase = blockIdx.x * 256;
    const int colBase = blockIdx.y * BN;

    __shared__ __align__(16) bf16 As[2 * 2 * 256 * 32];
    __shared__ __align__(16) bf16 Bs[2 * 2 * BN * 32];

    const int tid = threadIdx.x;
    const int w = tid >> 6;
    const int lane = tid & 63;
    const int wm = (BN == 256) ? (w >> 2) : (w >> 1);
    const int wn = (BN == 256) ? (w & 3) : (w & 1);
    const int lr = lane & 15, lc = lane >> 4;

    // staging: lane covers (row = tid>>2, swizzled 16B chunk) of a 128-row slab
    const int gchunk = (tid & 3) ^ ((tid >> 3) & 3);
    const bf16* Ag = A + (size_t)(rowBase + (tid >> 2)) * lda + gchunk * 8;
    const bf16* Bg = Bt + (size_t)(colBase + (tid >> 2)) * ldb + gchunk * 8;
    const size_t ldaL = (size_t)lda, ldbL = (size_t)ldb;
    bf16* AsW = As + w * 512;   // wave slice inside each staged 8KB half-slab
    bf16* BsW = Bs + w * 512;

    // fragment read bases (element offsets); read chunk XOR folds into base
    const int rchunk = lc ^ ((lr >> 1) & 3);
    const int aBase = wm * (AW * 32) + lr * 32 + rchunk * 8;
    const int bBase = wn * 2048 + lr * 32 + rchunk * 8;

#define STAGE_A(buf, ks, tau) do {                                         \
        const bf16* _g = Ag + (size_t)(tau) * 64 + (ks) * 32;              \
        bf16* _l = AsW + ((buf) * 2 + (ks)) * 8192;                        \
        gld_lds16(_g, _l);                                                 \
        gld_lds16(_g + 128 * ldaL, _l + 4096);                             \
    } while (0)

#define STAGE_B(buf, ks, tau) do {                                         \
        const bf16* _g = Bg + (size_t)(tau) * 64 + (ks) * 32;              \
        bf16* _l = BsW + ((buf) * 2 + (ks)) * (BN * 32);                   \
        gld_lds16(_g, _l);                                                 \
        if constexpr (BQ == 2) gld_lds16(_g + 128 * ldbL, _l + 4096);      \
    } while (0)

#define LOAD_AF(buf, ks) do {                                              \
        _Pragma("unroll")                                                  \
        for (int i = 0; i < FM; i++)                                       \
            af[i] = *(const bf16x8*)(As + aBase + ((buf) * 2 + (ks)) * 8192 \
                                     + i * 512);                           \
    } while (0)

#define LOAD_BF(buf, ks) do {                                              \
        _Pragma("unroll")                                                  \
        for (int j = 0; j < 4; j++)                                        \
            bfv[j] = *(const bf16x8*)(Bs + bBase + ((buf) * 2 + (ks)) * (BN * 32) \
                                      + j * 512);                          \
    } while (0)

#define MMAALL() do {                                                      \
        __builtin_amdgcn_s_setprio(1);                                     \
        _Pragma("unroll")                                                  \
        for (int i = 0; i < FM; i++)                                       \
            _Pragma("unroll")                                              \
            for (int j = 0; j < 4; j++)                                    \
                acc[i][j] = __builtin_amdgcn_mfma_f32_16x16x32_bf16(       \
                    af[i], bfv[j], acc[i][j], 0, 0, 0);                    \
        __builtin_amdgcn_s_setprio(0);                                     \
    } while (0)

#define BAR() __builtin_amdgcn_s_barrier()
#define VMCS() do {                                                        \
        if constexpr (BN == 256) asm volatile("s_waitcnt vmcnt(8)" ::: "memory"); \
        else                     asm volatile("s_waitcnt vmcnt(6)" ::: "memory"); \
    } while (0)
#define VMCH() do {                                                        \
        if constexpr (BN == 256) asm volatile("s_waitcnt vmcnt(4)" ::: "memory"); \
        else                     asm volatile("s_waitcnt vmcnt(3)" ::: "memory"); \
    } while (0)
#define VMC0() asm volatile("s_waitcnt vmcnt(0)" ::: "memory")

    f32x4 acc[FM][4] = {};
    bf16x8 af[FM], bfv[4];

    const int NT = K >> 6;  // K in {1024,2048,4096} -> NT even, >= 16

    // ---- prologue: slots in read order; groups of {A,B} keep vmcnt exact ----
    STAGE_A(0, 0, 0); STAGE_B(0, 0, 0);
    STAGE_A(0, 1, 0); STAGE_B(0, 1, 0);
    STAGE_A(1, 0, 1); STAGE_B(1, 0, 1);
    BAR();

    for (int t = 0; t < NT - 2; t += 2) {
        // ---- tile t (buf 0) ----
        VMCS();
        LOAD_AF(0, 0); LOAD_BF(0, 0);
        STAGE_A(1, 1, t + 1); STAGE_B(1, 1, t + 1);
        BAR(); MMAALL(); BAR();

        VMCS();
        LOAD_AF(0, 1); LOAD_BF(0, 1);
        STAGE_A(0, 0, t + 2); STAGE_B(0, 0, t + 2);
        BAR(); MMAALL(); BAR();

        // ---- tile t+1 (buf 1) ----
        VMCS();
        LOAD_AF(1, 0); LOAD_BF(1, 0);
        STAGE_A(0, 1, t + 2); STAGE_B(0, 1, t + 2);
        BAR(); MMAALL(); BAR();

        VMCS();
        LOAD_AF(1, 1); LOAD_BF(1, 1);
        STAGE_A(1, 0, t + 3); STAGE_B(1, 0, t + 3);
        BAR(); MMAALL(); BAR();
    }

    // ---- tail: tiles NT-2 (buf0), NT-1 (buf1); ladder 2g/2g/g/0 ----
    VMCS();
    LOAD_AF(0, 0); LOAD_BF(0, 0);
    STAGE_A(1, 1, NT - 1); STAGE_B(1, 1, NT - 1);
    BAR(); MMAALL(); BAR();

    VMCS();
    LOAD_AF(0, 1); LOAD_BF(0, 1);
    BAR(); MMAALL(); BAR();

    VMCH();
    LOAD_AF(1, 0); LOAD_BF(1, 0);
    BAR(); MMAALL(); BAR();

    VMC0();
    LOAD_AF(1, 1); LOAD_BF(1, 1);
    MMAALL();

#undef STAGE_A
#undef STAGE_B
#undef LOAD_AF
#undef LOAD_BF
#undef MMAALL
#undef BAR
#undef VMCS
#undef VMCH
#undef VMC0

    // ---- epilogue. C/D layout (16x16x32): col = lane&15, row = (lane>>4)*4 + reg ----
    float bval[4];
#pragma unroll
    for (int j = 0; j < 4; j++)
        bval[j] = bias ? bias[colBase + wn * 64 + j * 16 + lr] : 0.0f;

#pragma unroll
    for (int fi = 0; fi < FM; fi++) {
        const int row = rowBase + wm * AW + fi * 16 + lc * 4;
#pragma unroll
        for (int fj = 0; fj < 4; fj++) {
            const int col = colBase + wn * 64 + fj * 16 + lr;
#pragma unroll
            for (int r = 0; r < 4; r++) {
                float v = acc[fi][fj][r] * alpha + bval[fj];
                if constexpr (EPI == 1) v = fast_gelu(v);
                if constexpr (EPI == 2) v += resid[(size_t)(row + r) * ldc + col];
                Cout[(size_t)(row + r) * ldc + col] = (OutT)v;
            }
        }
    }
}

// ---------------------------------------------------------------------------
// LayerNorm over last dim (C=1024), fp32 in -> bf16 out. One block per row.
// ---------------------------------------------------------------------------
__launch_bounds__(256)
__global__ void ln_kernel(const float* __restrict__ x, const float* __restrict__ g,
                          const float* __restrict__ b, bf16* __restrict__ out) {
    __shared__ float red[4];
    const int row = blockIdx.x;
    const int tid = threadIdx.x;
    const float4* xr = (const float4*)(x + (size_t)row * C_DIM);
    float4 v = xr[tid];
    float s = v.x + v.y + v.z + v.w;
#pragma unroll
    for (int m = 32; m; m >>= 1) s += __shfl_xor(s, m, 64);
    if ((tid & 63) == 0) red[tid >> 6] = s;
    __syncthreads();
    const float mu = (red[0] + red[1] + red[2] + red[3]) * (1.0f / C_DIM);
    const float dx = v.x - mu, dy = v.y - mu, dz = v.z - mu, dw = v.w - mu;
    float q = dx * dx + dy * dy + dz * dz + dw * dw;
#pragma unroll
    for (int m = 32; m; m >>= 1) q += __shfl_xor(q, m, 64);
    __syncthreads();
    if ((tid & 63) == 0) red[tid >> 6] = q;
    __syncthreads();
    const float var = (red[0] + red[1] + red[2] + red[3]) * (1.0f / C_DIM);
    const float rs = rsqrtf(var + 1e-5f);
    const float4 gg = ((const float4*)g)[tid];
    const float4 bb = ((const float4*)b)[tid];
    bf16x4 o;
    o[0] = (bf16)(dx * rs * gg.x + bb.x);
    o[1] = (bf16)(dy * rs * gg.y + bb.y);
    o[2] = (bf16)(dz * rs * gg.z + bb.z);
    o[3] = (bf16)(dw * rs * gg.w + bb.w);
    ((bf16x4*)(out + (size_t)row * C_DIM))[tid] = o;
}

// ---------------------------------------------------------------------------
// Row softmax: S row (T=2048 bf16) -> P row (bf16). One block per row.
// ---------------------------------------------------------------------------
__launch_bounds__(256)
__global__ void softmax_kernel(const bf16* __restrict__ S, bf16* __restrict__ P) {
    __shared__ float red[4];
    const size_t base = (size_t)blockIdx.x * T_DIM;
    const int tid = threadIdx.x;
    bf16x8 sv = ((const bf16x8*)(S + base))[tid];
    float e[8];
#pragma unroll
    for (int i = 0; i < 8; i++) e[i] = (float)sv[i];
    float mx = e[0];
#pragma unroll
    for (int i = 1; i < 8; i++) mx = fmaxf(mx, e[i]);
#pragma unroll
    for (int m = 32; m; m >>= 1) mx = fmaxf(mx, __shfl_xor(mx, m, 64));
    if ((tid & 63) == 0) red[tid >> 6] = mx;
    __syncthreads();
    mx = fmaxf(fmaxf(red[0], red[1]), fmaxf(red[2], red[3]));
    float s = 0.0f;
#pragma unroll
    for (int i = 0; i < 8; i++) {
        e[i] = __expf(e[i] - mx);
        s += e[i];
    }
#pragma unroll
    for (int m = 32; m; m >>= 1) s += __shfl_xor(s, m, 64);
    __syncthreads();
    if ((tid & 63) == 0) red[tid >> 6] = s;
    __syncthreads();
    const float inv = 1.0f / (red[0] + red[1] + red[2] + red[3]);
    bf16x8 p;
#pragma unroll
    for (int i = 0; i < 8; i++) p[i] = (bf16)(e[i] * inv);
    ((bf16x8*)(P + base))[tid] = p;
}

// ---------------------------------------------------------------------------
// Merged transpose+convert for all 4 weight matrices (fp32 [R,Cc] -> bf16 [Cc,R]).
// ---------------------------------------------------------------------------
__global__ void transpose_f2b_all(const float* __restrict__ s0, bf16* __restrict__ d0,
                                  const float* __restrict__ s1, bf16* __restrict__ d1,
                                  const float* __restrict__ s2, bf16* __restrict__ d2,
                                  const float* __restrict__ s3, bf16* __restrict__ d3) {
    __shared__ float tile[32][33];
    int id = blockIdx.x;
    const float* src;
    bf16* dst;
    int R, Cc, local;
    if (id < 3072)       { src = s0; dst = d0; R = 1024; Cc = 3072; local = id; }
    else if (id < 4096)  { src = s1; dst = d1; R = 1024; Cc = 1024; local = id - 3072; }
    else if (id < 8192)  { src = s2; dst = d2; R = 1024; Cc = 4096; local = id - 4096; }
    else                 { src = s3; dst = d3; R = 4096; Cc = 1024; local = id - 8192; }
    const int tilesX = Cc >> 5;
    const int bx = (local % tilesX) * 32;
    const int by = (local / tilesX) * 32;
    const int tx = threadIdx.x, ty = threadIdx.y;
    for (int i = ty; i < 32; i += 8)
        tile[i][tx] = src[(size_t)(by + i) * Cc + bx + tx];
    __syncthreads();
    for (int i = ty; i < 32; i += 8)
        dst[(size_t)(bx + i) * R + by + tx] = (bf16)tile[tx][i];
}

// Transpose bf16 [R, Cc] (ld=ldsrc) -> bf16 [Cc, R] (ld=R), batched via z.
__global__ void transpose_b2b(const bf16* __restrict__ src, int ldsrc, long long sstride,
                              bf16* __restrict__ dst, long long dstride, int R) {
    __shared__ bf16 tile[32][33];
    src += (long long)blockIdx.z * sstride;
    dst += (long long)blockIdx.z * dstride;
    const int bx = blockIdx.x * 32;
    const int by = blockIdx.y * 32;
    const int tx = threadIdx.x, ty = threadIdx.y;
    for (int i = ty; i < 32; i += 8)
        tile[i][tx] = src[(size_t)(by + i) * ldsrc + bx + tx];
    __syncthreads();
    for (int i = ty; i < 32; i += 8)
        dst[(size_t)(bx + i) * R + by + tx] = tile[tx][i];
}

// ---------------------------------------------------------------------------
extern "C" void kernel_launch(void* const* d_in, const int* in_sizes, int n_in,
                              void* d_out, int out_size, void* d_ws, size_t ws_size,
                              hipStream_t stream) {
    const float* x      = (const float*)d_in[0];
    const float* ln1_g  = (const float*)d_in[1];
    const float* ln1_b  = (const float*)d_in[2];
    const float* w_attn = (const float*)d_in[3];
    const float* b_attn = (const float*)d_in[4];
    const float* w_proj = (const float*)d_in[5];
    const float* b_proj = (const float*)d_in[6];
    const float* ln2_g  = (const float*)d_in[7];
    const float* ln2_b  = (const float*)d_in[8];
    const float* w_fc   = (const float*)d_in[9];
    const float* b_fc   = (const float*)d_in[10];
    const float* w_mlp  = (const float*)d_in[11];
    const float* b_mlp  = (const float*)d_in[12];
    float* out = (float*)d_out;

    const int M = B_DIM * T_DIM;  // 8192

    char* base = (char*)d_ws;
    size_t off = 0;
    auto alloc = [&](size_t bytes) -> char* {
        char* p = base + off;
        off += (bytes + 255) & ~(size_t)255;
        return p;
    };
    bf16* wT_attn = (bf16*)alloc((size_t)3072 * 1024 * 2);
    bf16* wT_proj = (bf16*)alloc((size_t)1024 * 1024 * 2);
    bf16* wT_fc   = (bf16*)alloc((size_t)4096 * 1024 * 2);
    bf16* wT_mlp  = (bf16*)alloc((size_t)1024 * 4096 * 2);
    bf16* h       = (bf16*)alloc((size_t)M * 1024 * 2);        // h1, reused as h2
    bf16* qkv     = (bf16*)alloc((size_t)M * 3072 * 2);
    bf16* vT      = (bf16*)alloc((size_t)B_DIM * 1024 * 2048 * 2);
    bf16* S       = (bf16*)alloc((size_t)B_DIM * 2048 * 2048 * 2);
    bf16* P       = (bf16*)alloc((size_t)B_DIM * 2048 * 2048 * 2);
    bf16* y       = (bf16*)alloc((size_t)M * 1024 * 2);
    float* x2     = (float*)alloc((size_t)M * 1024 * 4);
    bf16* act     = (bf16*)S;  // alias: S+P dead after PV; 67MB needed, S+P = 67MB

    const dim3 tb(32, 8);

    // weight transpose+convert, all 4 in one launch
    transpose_f2b_all<<<12288, tb, 0, stream>>>(w_attn, wT_attn, w_proj, wT_proj,
                                                w_fc, wT_fc, w_mlp, wT_mlp);

    // h = LN1(x)
    ln_kernel<<<M, 256, 0, stream>>>(x, ln1_g, ln1_b, h);

    // qkv = h @ w_attn + b_attn   [8192, 3072]
    gemm8p<0, bf16, 128><<<dim3(32, 24, 1), 512, 0, stream>>>(
        h, 1024, 0, wT_attn, 1024, 0, qkv, 3072, 0, b_attn, nullptr, 0, 1.0f, 1024);

    // vT[b] = v[b]^T   (v = qkv cols [2C,3C))
    transpose_b2b<<<dim3(1024 / 32, 2048 / 32, B_DIM), tb, 0, stream>>>(
        qkv + 2 * C_DIM, 3072, (long long)T_DIM * 3072, vT, (long long)C_DIM * T_DIM, T_DIM);

    // S[b] = q[b] @ k[b]^T * (1/32)   [2048, 2048] bf16
    gemm8p<0, bf16, 256><<<dim3(8, 8, B_DIM), 512, 0, stream>>>(
        qkv, 3072, (long long)T_DIM * 3072,
        qkv + C_DIM, 3072, (long long)T_DIM * 3072,
        S, 2048, (long long)T_DIM * T_DIM, nullptr, nullptr, 0, 0.03125f, 1024);

    // P = softmax(S) rows
    softmax_kernel<<<B_DIM * T_DIM, 256, 0, stream>>>(S, P);

    // y[b] = P[b] @ v[b]   [2048, 1024] bf16
    gemm8p<0, bf16, 128><<<dim3(8, 8, B_DIM), 512, 0, stream>>>(
        P, 2048, (long long)T_DIM * T_DIM,
        vT, 2048, (long long)C_DIM * T_DIM,
        y, 1024, (long long)T_DIM * C_DIM, nullptr, nullptr, 0, 1.0f, 2048);

    // x2 = y @ w_proj + b_proj + x   [8192, 1024] fp32
    gemm8p<2, float, 128><<<dim3(32, 8, 1), 512, 0, stream>>>(
        y, 1024, 0, wT_proj, 1024, 0, x2, 1024, 0, b_proj, x, 0, 1.0f, 1024);

    // h2 = LN2(x2)  (reuse h buffer)
    ln_kernel<<<M, 256, 0, stream>>>(x2, ln2_g, ln2_b, h);

    // act = gelu(h2 @ w_fc + b_fc)   [8192, 4096] bf16
    gemm8p<1, bf16, 256><<<dim3(32, 16, 1), 512, 0, stream>>>(
        h, 1024, 0, wT_fc, 1024, 0, act, 4096, 0, b_fc, nullptr, 0, 1.0f, 1024);

    // out = act @ w_mlp_proj + b_mlp_proj + x2   [8192, 1024] fp32
    gemm8p<2, float, 128><<<dim3(32, 8, 1), 512, 0, stream>>>(
        act, 4096, 0, wT_mlp, 4096, 0, out, 1024, 0, b_mlp, x2, 0, 1.0f, 4096);
}